// Round 2
// baseline (500.086 us; speedup 1.0000x reference)
//
#include <hip/hip_runtime.h>
#include <hip/hip_bf16.h>

#define B_  4
#define S_  1024
#define DM_ 1024
#define H_  16
#define DK_ 64

typedef unsigned short u16;
typedef __attribute__((ext_vector_type(8))) short bf16x8;
typedef __attribute__((ext_vector_type(4))) float f32x4;

__device__ __forceinline__ float bf2f(u16 u) {
    union { unsigned int i; float f; } c;
    c.i = ((unsigned int)u) << 16;
    return c.f;
}
__device__ __forceinline__ u16 f2bf(float f) {
    union { float f; unsigned int i; } c;
    c.f = f;
    unsigned int x = c.i;
    unsigned int lsb = (x >> 16) & 1u;
    x += 0x7fffu + lsb;          // round-to-nearest-even
    return (u16)(x >> 16);
}

// ---------------------------------------------------------------------------
// Runtime dtype detection (graph-safe, device-side, same work every call).
// For fp32 inputs, even-index u16s are float LOW halves -> bits[14:7] are
// mantissa bits, uniform (~16% land in [100,140]). For bf16 inputs they are
// bf16 exponents of ~N(0,1) data (~100% in range). flag=1 -> inputs are fp32.
// ---------------------------------------------------------------------------
__global__ void detect_kernel(const u16* __restrict__ q, int* __restrict__ flag) {
    if (threadIdx.x == 0) {
        int cnt = 0;
        for (int i = 0; i < 256; ++i) {
            u16 u = q[2 * i];
            int e = (u >> 7) & 0xFF;
            cnt += (e >= 100 && e <= 140) ? 1 : 0;
        }
        *flag = (cnt < 128) ? 1 : 0;
    }
}

// ---------------------------------------------------------------------------
// Generic GEMM: C[m,n] = act(sum_k A[m,k]*W[n,k] + bias[n]); bf16 MFMA, fp32
// accum. A:(M,K) row-major, W:(N,K) row-major. 64x64 tile, 4 waves; wave owns
// a 16x64 slab (4 col-tiles of mfma_f32_16x16x32_bf16).
// A_DYN/W_DYN/OUT_DYN: operand dtype decided by runtime *flag (1=fp32).
// ---------------------------------------------------------------------------
template<int ACT, int A_DYN, int W_DYN, int OUT_DYN>
__global__ __launch_bounds__(256) void gemm_bias_kernel(
    const void* __restrict__ Ap, const void* __restrict__ Wp,
    const void* __restrict__ biasp, void* __restrict__ Cp,
    int M, int N, int K, const int* __restrict__ flag)
{
    __shared__ __align__(16) u16 As[64][72];   // +8 pad: 2-way LDS conflict (free)
    __shared__ __align__(16) u16 Ws[64][72];

    const int f    = (A_DYN || W_DYN || OUT_DYN) ? *flag : 0;
    const bool af32 = A_DYN && f;
    const bool wf32 = W_DYN && f;

    const int m0   = blockIdx.y * 64;
    const int n0   = blockIdx.x * 64;
    const int tid  = threadIdx.x;
    const int w    = tid >> 6;
    const int lane = tid & 63;
    const int l16  = lane & 15;
    const int quad = lane >> 4;

    f32x4 acc[4];
#pragma unroll
    for (int i = 0; i < 4; ++i) acc[i] = (f32x4){0.f, 0.f, 0.f, 0.f};

    for (int k0 = 0; k0 < K; k0 += 64) {
        for (int c = tid; c < 512; c += 256) {
            int row = c >> 3, cc = (c & 7) * 8;
            if (af32) {
                const float* ap = (const float*)Ap + (size_t)(m0 + row) * K + k0 + cc;
                float4 x = *(const float4*)ap, y = *(const float4*)(ap + 4);
                u16 t[8] = {f2bf(x.x), f2bf(x.y), f2bf(x.z), f2bf(x.w),
                            f2bf(y.x), f2bf(y.y), f2bf(y.z), f2bf(y.w)};
                *(uint4*)&As[row][cc] = *(uint4*)t;
            } else {
                *(uint4*)&As[row][cc] =
                    *(const uint4*)((const u16*)Ap + (size_t)(m0 + row) * K + k0 + cc);
            }
            if (wf32) {
                const float* wp = (const float*)Wp + (size_t)(n0 + row) * K + k0 + cc;
                float4 x = *(const float4*)wp, y = *(const float4*)(wp + 4);
                u16 t[8] = {f2bf(x.x), f2bf(x.y), f2bf(x.z), f2bf(x.w),
                            f2bf(y.x), f2bf(y.y), f2bf(y.z), f2bf(y.w)};
                *(uint4*)&Ws[row][cc] = *(uint4*)t;
            } else {
                *(uint4*)&Ws[row][cc] =
                    *(const uint4*)((const u16*)Wp + (size_t)(n0 + row) * K + k0 + cc);
            }
        }
        __syncthreads();
#pragma unroll
        for (int kk = 0; kk < 2; ++kk) {
            bf16x8 a = *(const bf16x8*)&As[w * 16 + l16][kk * 32 + quad * 8];
#pragma unroll
            for (int ct = 0; ct < 4; ++ct) {
                bf16x8 b = *(const bf16x8*)&Ws[ct * 16 + l16][kk * 32 + quad * 8];
                acc[ct] = __builtin_amdgcn_mfma_f32_16x16x32_bf16(a, b, acc[ct], 0, 0, 0);
            }
        }
        __syncthreads();
    }

    // C/D layout: row = quad*4 + r, col = l16 (verified m89/m91)
#pragma unroll
    for (int ct = 0; ct < 4; ++ct) {
        int col = n0 + ct * 16 + l16;
        float bv = wf32 ? ((const float*)biasp)[col] : bf2f(((const u16*)biasp)[col]);
#pragma unroll
        for (int r = 0; r < 4; ++r) {
            int row = m0 + w * 16 + quad * 4 + r;
            float v = acc[ct][r] + bv;
            if (ACT) v = v > 0.f ? v : 0.f;
            size_t idx = (size_t)row * N + col;
            if (OUT_DYN && f) ((float*)Cp)[idx] = v;
            else              ((u16*)Cp)[idx]   = f2bf(v);
        }
    }
}

// ---------------------------------------------------------------------------
// Fused attention, flash-style. One block = one (b, h, 64-row q-tile).
// All head tensors addressed as buf[(b*S + s)*DM + h*DK + d].
// out[q,d] = (1/l) * sum_k exp(kq[q,k]-m) * qv[q,k] * Kp[k,d]
// ---------------------------------------------------------------------------
__global__ __launch_bounds__(256) void attn_kernel(
    const u16* __restrict__ q1, const u16* __restrict__ q2,
    const u16* __restrict__ kr, const u16* __restrict__ vr,
    const u16* __restrict__ kp, const int* __restrict__ mask,
    u16* __restrict__ om)
{
    __shared__ __align__(16) u16 q1s[64][72];
    __shared__ __align__(16) u16 q2s[64][72];
    __shared__ __align__(16) u16 krs[64][72];
    __shared__ __align__(16) u16 vrs[64][72];
    __shared__ __align__(16) u16 kts[64][72];     // Kp tile transposed: kts[d][k]
    __shared__ __align__(16) u16 pts[4][16][72];  // per-wave P-tilde staging

    const int qt   = blockIdx.x;
    const int h    = blockIdx.y;
    const int b    = blockIdx.z;
    const int q0   = qt * 64;
    const int tid  = threadIdx.x;
    const int w    = tid >> 6;
    const int lane = tid & 63;
    const int l16  = lane & 15;
    const int quad = lane >> 4;

    const size_t base = (size_t)b * S_ * DM_ + (size_t)h * DK_;

    for (int c = tid; c < 512; c += 256) {
        int row = c >> 3, cc = (c & 7) * 8;
        *(uint4*)&q1s[row][cc] = *(const uint4*)&q1[base + (size_t)(q0 + row) * DM_ + cc];
        *(uint4*)&q2s[row][cc] = *(const uint4*)&q2[base + (size_t)(q0 + row) * DM_ + cc];
    }

    float m_run[4], l_run[4];
    f32x4 oacc[4];
#pragma unroll
    for (int r = 0; r < 4; ++r) { m_run[r] = -1e30f; l_run[r] = 0.f; }
#pragma unroll
    for (int ct = 0; ct < 4; ++ct) oacc[ct] = (f32x4){0.f, 0.f, 0.f, 0.f};

    for (int kt = 0; kt < S_ / 64; ++kt) {
        const int k0 = kt * 64;
        __syncthreads();   // protects prior iter's LDS reads + first-iter q stage
        for (int c = tid; c < 512; c += 256) {
            int row = c >> 3, cc = (c & 7) * 8;
            *(uint4*)&krs[row][cc] = *(const uint4*)&kr[base + (size_t)(k0 + row) * DM_ + cc];
            *(uint4*)&vrs[row][cc] = *(const uint4*)&vr[base + (size_t)(k0 + row) * DM_ + cc];
            union { uint4 v; u16 u[8]; } kv;
            kv.v = *(const uint4*)&kp[base + (size_t)(k0 + row) * DM_ + cc];
#pragma unroll
            for (int j = 0; j < 8; ++j) kts[cc + j][row] = kv.u[j];
        }
        __syncthreads();

        f32x4 s1[4], s2[4];
#pragma unroll
        for (int ct = 0; ct < 4; ++ct) {
            s1[ct] = (f32x4){0.f, 0.f, 0.f, 0.f};
            s2[ct] = (f32x4){0.f, 0.f, 0.f, 0.f};
        }
#pragma unroll
        for (int kk = 0; kk < 2; ++kk) {
            bf16x8 a1 = *(const bf16x8*)&q1s[w * 16 + l16][kk * 32 + quad * 8];
            bf16x8 a2 = *(const bf16x8*)&q2s[w * 16 + l16][kk * 32 + quad * 8];
#pragma unroll
            for (int ct = 0; ct < 4; ++ct) {
                bf16x8 b1 = *(const bf16x8*)&krs[ct * 16 + l16][kk * 32 + quad * 8];
                bf16x8 b2 = *(const bf16x8*)&vrs[ct * 16 + l16][kk * 32 + quad * 8];
                s1[ct] = __builtin_amdgcn_mfma_f32_16x16x32_bf16(a1, b1, s1[ct], 0, 0, 0);
                s2[ct] = __builtin_amdgcn_mfma_f32_16x16x32_bf16(a2, b2, s2[ct], 0, 0, 0);
            }
        }

        float tmax[4] = {-1e30f, -1e30f, -1e30f, -1e30f};
#pragma unroll
        for (int ct = 0; ct < 4; ++ct) {
            int kc = k0 + ct * 16 + l16;
#pragma unroll
            for (int r = 0; r < 4; ++r) {
                int qrow = q0 + w * 16 + quad * 4 + r;
                int mv = mask[((size_t)b * S_ + qrow) * S_ + kc];
                float v = s1[ct][r];
                if (mv == 0) v = -1e9f;
                s1[ct][r] = v;
                tmax[r] = fmaxf(tmax[r], v);
            }
        }
#pragma unroll
        for (int off = 1; off < 16; off <<= 1)
#pragma unroll
            for (int r = 0; r < 4; ++r)
                tmax[r] = fmaxf(tmax[r], __shfl_xor(tmax[r], off, 64));

        float alpha[4], newm[4];
#pragma unroll
        for (int r = 0; r < 4; ++r) {
            newm[r]  = fmaxf(m_run[r], tmax[r]);
            alpha[r] = __expf(m_run[r] - newm[r]);
            m_run[r] = newm[r];
        }

        float psum[4] = {0.f, 0.f, 0.f, 0.f};
#pragma unroll
        for (int ct = 0; ct < 4; ++ct)
#pragma unroll
            for (int r = 0; r < 4; ++r) {
                float p = __expf(s1[ct][r] - newm[r]);
                psum[r] += p;
                pts[w][quad * 4 + r][ct * 16 + l16] = f2bf(p * s2[ct][r]);
            }
#pragma unroll
        for (int off = 1; off < 16; off <<= 1)
#pragma unroll
            for (int r = 0; r < 4; ++r)
                psum[r] += __shfl_xor(psum[r], off, 64);
#pragma unroll
        for (int r = 0; r < 4; ++r) l_run[r] = l_run[r] * alpha[r] + psum[r];
#pragma unroll
        for (int ct = 0; ct < 4; ++ct)
#pragma unroll
            for (int r = 0; r < 4; ++r) oacc[ct][r] *= alpha[r];

        // O += P~ @ Kp_tile  (same-wave LDS RAW on pts: DS ops are in-order per wave)
#pragma unroll
        for (int kk = 0; kk < 2; ++kk) {
            bf16x8 a = *(const bf16x8*)&pts[w][l16][kk * 32 + quad * 8];
#pragma unroll
            for (int ct = 0; ct < 4; ++ct) {
                bf16x8 bb = *(const bf16x8*)&kts[ct * 16 + l16][kk * 32 + quad * 8];
                oacc[ct] = __builtin_amdgcn_mfma_f32_16x16x32_bf16(a, bb, oacc[ct], 0, 0, 0);
            }
        }
    }

#pragma unroll
    for (int ct = 0; ct < 4; ++ct)
#pragma unroll
        for (int r = 0; r < 4; ++r) {
            int row = q0 + w * 16 + quad * 4 + r;
            int col = ct * 16 + l16;
            float v = oacc[ct][r] / l_run[r];
            om[base + (size_t)row * DM_ + col] = f2bf(v);
        }
}

// ---------------------------------------------------------------------------
extern "C" void kernel_launch(void* const* d_in, const int* in_sizes, int n_in,
                              void* d_out, int out_size, void* d_ws, size_t ws_size,
                              hipStream_t stream)
{
    const void* query = d_in[0];
    const void* key   = d_in[1];
    const void* value = d_in[2];
    const int*  mask  = (const int*)d_in[3];
    const void* Wq  = d_in[4];  const void* bq  = d_in[5];
    const void* Wk  = d_in[6];  const void* bk  = d_in[7];
    const void* Wv  = d_in[8];  const void* bv  = d_in[9];
    const void* Wo  = d_in[10]; const void* bo  = d_in[11];
    const void* Wkl = d_in[12]; const void* bkl = d_in[13];
    const void* Wql = d_in[14]; const void* bql = d_in[15];
    const void* Wq2 = d_in[16]; const void* bq2 = d_in[17];
    const void* Wvl = d_in[18]; const void* bvl = d_in[19];
    const void* Wel = d_in[20]; const void* bel = d_in[21];

    int* flag = (int*)d_ws;
    u16* ws   = (u16*)((char*)d_ws + 16);
    const size_t BUF = (size_t)(B_ * S_) * DM_;   // 4M elements = 8 MB bf16
    u16* Qp  = ws + 0 * BUF;
    u16* Kp  = ws + 1 * BUF;
    u16* Vp  = ws + 2 * BUF;
    u16* krb = ws + 3 * BUF;
    u16* q1a = ws + 4 * BUF;
    u16* q1b = ws + 5 * BUF;
    u16* q2r = ws + 6 * BUF;
    u16* vrb = ws + 7 * BUF;
    u16* Om  = ws + 8 * BUF;

    const int M = B_ * S_;            // 4096
    dim3 blk(256);
    dim3 gBig(DM_ / 64, M / 64);      // (16, 64)
    dim3 gSm(1, (M * H_) / 64);       // (1, 1024): M=65536, N=K=64

    detect_kernel<<<1, 64, 0, stream>>>((const u16*)query, flag);

    // projections: A and W dtype-dynamic, out bf16 ws
    gemm_bias_kernel<0,1,1,0><<<gBig, blk, 0, stream>>>(query, Wq, bq, Qp, M, DM_, DM_, flag);
    gemm_bias_kernel<0,1,1,0><<<gBig, blk, 0, stream>>>(key,   Wk, bk, Kp, M, DM_, DM_, flag);
    gemm_bias_kernel<0,1,1,0><<<gBig, blk, 0, stream>>>(value, Wv, bv, Vp, M, DM_, DM_, flag);

    // per-head refinements as (65536,64)x(64,64) GEMMs; A is ws bf16, W dynamic
    gemm_bias_kernel<1,0,1,0><<<gSm, blk, 0, stream>>>(Kp,  Wkl, bkl, krb, M * H_, DK_, DK_, flag);
    gemm_bias_kernel<1,0,1,0><<<gSm, blk, 0, stream>>>(Qp,  Wql, bql, q1a, M * H_, DK_, DK_, flag);
    gemm_bias_kernel<1,0,1,0><<<gSm, blk, 0, stream>>>(q1a, Wel, bel, q1b, M * H_, DK_, DK_, flag);
    gemm_bias_kernel<1,0,1,0><<<gSm, blk, 0, stream>>>(Qp,  Wq2, bq2, q2r, M * H_, DK_, DK_, flag);
    gemm_bias_kernel<1,0,1,0><<<gSm, blk, 0, stream>>>(Vp,  Wvl, bvl, vrb, M * H_, DK_, DK_, flag);

    // fused attention -> merged (B,S,DM) layout (all-bf16 operands)
    dim3 gA(S_ / 64, H_, B_);         // (16,16,4)
    attn_kernel<<<gA, blk, 0, stream>>>(q1b, q2r, krb, vrb, Kp, mask, Om);

    // output projection straight into d_out; out dtype runtime-selected
    gemm_bias_kernel<0,0,1,1><<<gBig, blk, 0, stream>>>(Om, Wo, bo, d_out, M, DM_, DM_, flag);
}